// Round 8
// baseline (1083.720 us; speedup 1.0000x reference)
//
#include <hip/hip_runtime.h>

typedef unsigned short u16;
typedef unsigned int u32;

constexpr int Bc = 2, Sc = 2048, Dc = 2048, Hc = 16, HDc = 128;

using short8 = __attribute__((ext_vector_type(8))) short;
using f32x4v = __attribute__((ext_vector_type(4))) float;

static __device__ __forceinline__ float bf2f(u16 v) { return __uint_as_float(((u32)v) << 16); }
static __device__ __forceinline__ u16 f2bf(float f) {
    u32 u = __float_as_uint(f);
    return (u16)((u + 0x7fffu + ((u >> 16) & 1u)) >> 16);
}

// async global->LDS, 16B per lane; LDS dest = wave-uniform base + lane*16
__device__ __forceinline__ void gll16(const u16* g, u16* l) {
    __builtin_amdgcn_global_load_lds((const __attribute__((address_space(1))) void*)g,
                                     (__attribute__((address_space(3))) void*)l, 16, 0, 0);
}

#define FENCE asm volatile("" ::: "memory")
#define BARX do { FENCE; __builtin_amdgcn_s_barrier(); FENCE; } while (0)

// ---------------- RoPE cos/sin tables: [S][64] fp32 ----------------
__global__ __launch_bounds__(256) void rope_tab_k(float* __restrict__ ctab, float* __restrict__ stab) {
    int idx = blockIdx.x * 256 + threadIdx.x; // S*64 threads
    int s = idx >> 6, i = idx & 63;
    float freq = exp2f(-(float)i * 0.20762050593045952f); // 10000^(-i/64)
    float ang = (float)s * freq;
    float c, sn;
    sincosf(ang, &sn, &c);
    ctab[idx] = c;
    stab[idx] = sn;
}

// ---------------- fp32 -> bf16 bulk convert ----------------
__global__ __launch_bounds__(256) void cvt_k(const float* __restrict__ in, u16* __restrict__ out, int n) {
    int i = (blockIdx.x * 256 + threadIdx.x) * 8;
    if (i >= n) return;
    float4 a = *(const float4*)(in + i);
    float4 b = *(const float4*)(in + i + 4);
    u16 r[8] = {f2bf(a.x), f2bf(a.y), f2bf(a.z), f2bf(a.w),
                f2bf(b.x), f2bf(b.y), f2bf(b.z), f2bf(b.w)};
    *(uint4*)(out + i) = *(uint4*)r;
}

// ---------------- fp32 W (R x C) -> bf16 Wt (C x R), 64x64 tiles; z selects source ----------------
__global__ __launch_bounds__(256) void tcvt3_k(const float* __restrict__ in0, const float* __restrict__ in1,
                                               const float* __restrict__ in2, u16* __restrict__ out,
                                               int R, int C) {
    __shared__ u16 tile[64][68];
    const float* in = (blockIdx.z == 0) ? in0 : (blockIdx.z == 1) ? in1 : in2;
    u16* o = out + (size_t)blockIdx.z * R * C;
    int bx = blockIdx.x * 64, by = blockIdx.y * 64;
    int t = threadIdx.x;
    int r = t >> 4, c4 = (t & 15) * 4;
    #pragma unroll
    for (int i = 0; i < 4; ++i) {
        int row = by + r + i * 16;
        float4 v = *(const float4*)(in + (size_t)row * C + bx + c4);
        u16* d = &tile[r + i * 16][c4];
        d[0] = f2bf(v.x); d[1] = f2bf(v.y); d[2] = f2bf(v.z); d[3] = f2bf(v.w);
    }
    __syncthreads();
    int oc = t >> 4, r4 = (t & 15) * 4;
    #pragma unroll
    for (int i = 0; i < 4; ++i) {
        int orow = oc + i * 16;
        u16 v[4] = {tile[r4][orow], tile[r4 + 1][orow], tile[r4 + 2][orow], tile[r4 + 3][orow]};
        *(uint2*)&o[(size_t)(bx + orow) * R + by + r4] = *(const uint2*)v;
    }
}

// ================= QKV GEMM: 128x384, BK=32, 2-buffer, 2 blocks/CU, counted vmcnt ====
// A: M x K bf16 (4096 x 2048); Bt: N x K bf16 (6144 = [WqT;WkT;WvT]).
// 512 blocks, ALL co-resident (2 blocks/CU via 64 KiB LDS): no round quantization,
// and the co-resident block's MFMA bursts fill this block's ds_read/barrier stalls.
// Per K-tile: {stage(t+1) | vmcnt(4)=tile t resident | bar | 10 ds_read | lgk0 |
//              setprio(1) 24 MFMA setprio(0) | bar}.  vmcnt never drains mid-loop.
// Epilogue: 3 col-chunks of 128 (each = one head): Q/K +RoPE, V -> V^T (B,H,HD,S).

#define QT2(RB, KST, SB, LAST) do { \
    if (!(LAST)) { stage((KST), (SB)); \
        asm volatile("s_waitcnt vmcnt(4)" ::: "memory"); } \
    else asm volatile("s_waitcnt vmcnt(0)" ::: "memory"); \
    BARX; \
    short8 aF[4], bF[6]; \
    _Pragma("unroll") for (int m_ = 0; m_ < 4; ++m_) \
        aF[m_] = *(const short8*)((RB) + (wm * 64 + m_ * 16 + ln) * 32 + co); \
    _Pragma("unroll") for (int n_ = 0; n_ < 6; ++n_) \
        bF[n_] = *(const short8*)((RB) + 4096 + (wn * 96 + n_ * 16 + ln) * 32 + co); \
    asm volatile("s_waitcnt lgkmcnt(0)" ::: "memory"); \
    __builtin_amdgcn_s_setprio(1); \
    _Pragma("unroll") for (int m_ = 0; m_ < 4; ++m_) \
    _Pragma("unroll") for (int n_ = 0; n_ < 6; ++n_) \
        acc[m_][n_] = __builtin_amdgcn_mfma_f32_16x16x32_bf16(aF[m_], bF[n_], acc[m_][n_], 0, 0, 0); \
    __builtin_amdgcn_s_setprio(0); \
    BARX; \
} while (0)

__global__ __launch_bounds__(512, 4) void gemm_qkv2b(
        const u16* __restrict__ A, const u16* __restrict__ Bt,
        u16* __restrict__ Oq, u16* __restrict__ Ok, u16* __restrict__ Ov,
        const float* __restrict__ ctab, const float* __restrict__ stab) {
    __shared__ u16 SM[32768]; // 64 KiB: 2 buffers x {A 128x32 (8KB), B 384x32 (24KB)}
    constexpr int K = Dc;     // 2048 -> 64 K-tiles of 32
    int t = threadIdx.x, wid = t >> 6, lane = t & 63;
    int wm = wid >> 2, wn = wid & 3;          // 2 x 4 wave grid; wave tile 64 x 96
    int ln = lane & 15, lq = lane >> 4;

    // XCD-aware bijective swizzle (nwg = 512 = 8 x 64); n-major chunks per XCD
    int lin = blockIdx.x;
    int swzb = (lin & 7) * 64 + (lin >> 3);
    int n0 = (swzb >> 5) * 384;      // 16 n-cols
    int m0 = (swzb & 31) * 128;      // 32 m-rows

    // stage K-tile kt into buffer b. LDS written LINEARLY by global_load_lds;
    // read-side chunk swizzle (cs ^= (row>>1)&3) realized on the GLOBAL source.
    auto stage = [&](int kt, int b) {
        u16* Ad = SM + b * 16384;
        u16* Bd = SM + b * 16384 + 4096;
        {
            int row = t >> 2, cs = t & 3; // A: 128x32, 512 chunks of 16B
            gll16(A + (size_t)(m0 + row) * K + kt * 32 + ((cs ^ ((row >> 1) & 3)) << 3),
                  Ad + (wid * 64) * 8);
        }
        #pragma unroll
        for (int L = 0; L < 3; ++L) {
            int ci = L * 512 + t;         // B: 384x32, 1536 chunks
            int row = ci >> 2, cs = ci & 3;
            gll16(Bt + (size_t)(n0 + row) * K + kt * 32 + ((cs ^ ((row >> 1) & 3)) << 3),
                  Bd + (L * 512 + wid * 64) * 8);
        }
    };

    int co = ((lq ^ ((ln >> 1) & 3)) << 3); // swizzled read chunk (row bases are 0 mod 8)
    f32x4v acc[4][6] = {};

    // prologue: tile 0 staged; residency enforced by first QT2's vmcnt(4)
    stage(0, 0);

    // main: alternate buffers; stage(t+1) at tile t; last tile drains
    #pragma unroll 1
    for (int kt = 0; kt < 62; kt += 2) {
        QT2(SM,         kt + 1, 1, 0);
        QT2(SM + 16384, kt + 2, 0, 0);
    }
    QT2(SM,         63, 1, 0);  // tile 62, stage 63
    QT2(SM + 16384,  0, 0, 1);  // tile 63 (tail: vmcnt(0))

    // ---- epilogue: 3 col-chunks of 128 through a 128 x 130 bf16 strip ----
    int b_ = m0 >> 11;
    int s0 = m0 & (Sc - 1);
    u16* Es = SM;
    const int ESTR = 130;

    for (int c = 0; c < 3; ++c) {
        #pragma unroll
        for (int nf = 0; nf < 6; ++nf) {
            int cg = wn * 96 + nf * 16;
            if ((cg >> 7) == c) {
                int col = cg & 127;
                #pragma unroll
                for (int mf = 0; mf < 4; ++mf)
                    #pragma unroll
                    for (int r = 0; r < 4; ++r)
                        Es[(wm * 64 + mf * 16 + (lq << 2) + r) * ESTR + col + ln] =
                            f2bf(acc[mf][nf][r]);
            }
        }
        __syncthreads();

        int gcol = n0 + c * 128;
        int which = gcol >> 11;          // 0=Q,1=K,2=V
        int h = (gcol & 2047) >> 7;
        if (which < 2) {
            // Q or K +RoPE: thread t -> row rh=t>>2, half h2=t&1, j-half jh=(t>>1)&1
            u16* dst0 = which ? Ok : Oq;
            int rh = t >> 2, h2 = t & 1, jh = (t >> 1) & 1;
            int s = s0 + rh;
            const u16* rowp = Es + rh * ESTR;
            const float* ct = ctab + (size_t)s * 64;
            const float* st = stab + (size_t)s * 64;
            u16* dp = dst0 + (((size_t)(b_ * Hc + h)) * Sc + s) * HDc + h2 * 64;
            #pragma unroll
            for (int j8 = jh * 32; j8 < jh * 32 + 32; j8 += 8) {
                uint4 aa = *(const uint4*)(rowp + j8);
                uint4 bb = *(const uint4*)(rowp + 64 + j8);
                const u16* ap8 = (const u16*)&aa;
                const u16* bp8 = (const u16*)&bb;
                float4 c0f = *(const float4*)(ct + j8);
                float4 c1f = *(const float4*)(ct + j8 + 4);
                float4 sn0 = *(const float4*)(st + j8);
                float4 sn1 = *(const float4*)(st + j8 + 4);
                float cc[8] = {c0f.x, c0f.y, c0f.z, c0f.w, c1f.x, c1f.y, c1f.z, c1f.w};
                float ss[8] = {sn0.x, sn0.y, sn0.z, sn0.w, sn1.x, sn1.y, sn1.z, sn1.w};
                u16 ov[8];
                #pragma unroll
                for (int e = 0; e < 8; ++e) {
                    float x1 = bf2f(ap8[e]), x2 = bf2f(bp8[e]);
                    ov[e] = h2 ? f2bf(x2 * cc[e] + x1 * ss[e]) : f2bf(x1 * cc[e] - x2 * ss[e]);
                }
                *(uint4*)(dp + j8) = *(const uint4*)ov;
            }
        } else {
            // V^T: thread t -> col d=t>>2, s-quarter sh=t&3 (32 rows each)
            int d = t >> 2, sh = t & 3;
            u16* dp = Ov + (((size_t)(b_ * Hc + h)) * HDc + d) * Sc + s0 + sh * 32;
            #pragma unroll
            for (int r8 = 0; r8 < 32; r8 += 8) {
                u16 ov[8];
                #pragma unroll
                for (int e = 0; e < 8; ++e)
                    ov[e] = Es[(sh * 32 + r8 + e) * ESTR + d];
                *(uint4*)(dp + r8) = *(const uint4*)ov;
            }
        }
        __syncthreads();
    }
}

// ================= out-proj GEMM: 128x256 BK=64 8-wave triple-buffer ================
// A = ctx bf16 (4096 x 2048), Bt = Wo^T bf16 (2048 x 2048), C2 fp32 (4096 x 2048).
// grid 8 x 32 = 256 blocks = exactly 1 round of 256 CUs.

#define RDA8(P) do { _Pragma("unroll") for (int m_ = 0; m_ < 4; ++m_) { \
    aG[m_][0] = *(const short8*)((P) + m_ * 1024 + co0); \
    aG[m_][1] = *(const short8*)((P) + m_ * 1024 + co1); } } while (0)

#define RDB2(P, nh) do { _Pragma("unroll") for (int j_ = 0; j_ < 2; ++j_) { \
    bG[j_][0] = *(const short8*)((P) + ((nh) * 2 + j_) * 1024 + co0); \
    bG[j_][1] = *(const short8*)((P) + ((nh) * 2 + j_) * 1024 + co1); } } while (0)

#define MFQ8(nh) do { _Pragma("unroll") for (int m_ = 0; m_ < 4; ++m_) \
    _Pragma("unroll") for (int j_ = 0; j_ < 2; ++j_) { \
    f32x4v& c_ = acc[m_][(nh) * 2 + j_]; \
    c_ = __builtin_amdgcn_mfma_f32_16x16x32_bf16(aG[m_][0], bG[j_][0], c_, 0, 0, 0); \
    c_ = __builtin_amdgcn_mfma_f32_16x16x32_bf16(aG[m_][1], bG[j_][1], c_, 0, 0, 0); } } while (0)

#define PT(nh) do { BARX; \
    asm volatile("s_waitcnt lgkmcnt(0)" ::: "memory"); \
    __builtin_amdgcn_s_setprio(1); MFQ8(nh); __builtin_amdgcn_s_setprio(0); \
    BARX; } while (0)

#define KTILE(aRb, bRb, KST, ADST, BDST, VW) do { \
    RDA8(aRb); RDB2(bRb, 0); \
    if ((KST) >= 0) stageA(KST, ADST); \
    PT(0); \
    RDB2(bRb, 1); \
    if ((KST) >= 0) stageB(KST, BDST); \
    if ((VW) == 6) asm volatile("s_waitcnt vmcnt(6)" ::: "memory"); \
    else if ((VW) == 0) asm volatile("s_waitcnt vmcnt(0)" ::: "memory"); \
    PT(1); } while (0)

__global__ __launch_bounds__(512, 2) void gemm128_op(
        const u16* __restrict__ A, const u16* __restrict__ Bt, float* __restrict__ C2) {
    __shared__ u16 SM[73728]; // 144 KiB: A x3 (16KB each) + B x3 (32KB each)
    constexpr int K = Dc;     // 2048 -> 32 K-tiles of 64
    constexpr int NT = 32;
    constexpr int N = Dc;
    int t = threadIdx.x, wid = t >> 6, lane = t & 63;
    int wm = wid >> 2, wn = wid & 3;          // 2 x 4 wave grid; wave tile 64 x 64
    int ln = lane & 15, lq = lane >> 4;

    // XCD-aware bijective swizzle (nwg = 256)
    int nx = gridDim.x; // 8
    int lin = blockIdx.y * nx + blockIdx.x;
    int cpx = (nx * gridDim.y) >> 3; // 32
    int swzb = (lin & 7) * cpx + (lin >> 3);
    int n0 = (swzb % nx) << 8;
    int m0 = (swzb / nx) << 7;

    u16* As0 = SM;
    u16* As1 = SM + 8192;
    u16* As2 = SM + 16384;
    u16* Bs0 = SM + 24576;
    u16* Bs1 = SM + 40960;
    u16* Bs2 = SM + 57344;

    auto stageA = [&](int kt, u16* dst) {
        #pragma unroll
        for (int L = 0; L < 2; ++L) {
            int ch16 = L * 512 + wid * 64 + lane; // 16B-chunk index, 128x64 tile
            int row = ch16 >> 3, ch = ch16 & 7;
            gll16(A + (size_t)(m0 + row) * K + kt * 64 + ((ch ^ (row & 7)) << 3),
                  dst + (L * 512 + wid * 64) * 8);
        }
    };
    auto stageB = [&](int kt, u16* dst) {
        #pragma unroll
        for (int L = 0; L < 4; ++L) {
            int ch16 = L * 512 + wid * 64 + lane; // 16B-chunk index, 256x64 tile
            int row = ch16 >> 3, ch = ch16 & 7;
            gll16(Bt + (size_t)(n0 + row) * K + kt * 64 + ((ch ^ (row & 7)) << 3),
                  dst + (L * 512 + wid * 64) * 8);
        }
    };

    const u16* aR0 = As0 + (wm * 64 + ln) * 64;
    const u16* aR1 = As1 + (wm * 64 + ln) * 64;
    const u16* aR2 = As2 + (wm * 64 + ln) * 64;
    const u16* bR0 = Bs0 + (wn * 64 + ln) * 64;
    const u16* bR1 = Bs1 + (wn * 64 + ln) * 64;
    const u16* bR2 = Bs2 + (wn * 64 + ln) * 64;
    int sw = ln & 7;
    int co0 = (lq ^ sw) << 3;        // k-slice 0 chunk (swizzled), u16 units
    int co1 = ((4 | lq) ^ sw) << 3;  // k-slice 1 chunk

    short8 aG[4][2], bG[2][2];
    f32x4v acc[4][4] = {};

    stageA(0, As0); stageB(0, Bs0);
    stageA(1, As1); stageB(1, Bs1);
    asm volatile("s_waitcnt vmcnt(6)" ::: "memory"); // kt0 resident, kt1 in flight
    BARX;

    for (int k3 = 0; k3 < NT - 2; k3 += 3) {
        KTILE(aR0, bR0, k3 + 2, As2, Bs2, 6);
        KTILE(aR1, bR1, k3 + 3, As0, Bs0, 6);
        KTILE(aR2, bR2, k3 + 4, As1, Bs1, 6);
    }
    KTILE(aR0, bR0, -1, As0, Bs0, 0);  // kt=30; drain so kt31 resident
    KTILE(aR1, bR1, -1, As0, Bs0, -1); // kt=31

    int rb = m0 + wm * 64 + (lq << 2);
    int cb = n0 + wn * 64 + ln;
    #pragma unroll
    for (int mf = 0; mf < 4; ++mf)
        #pragma unroll
        for (int nf = 0; nf < 4; ++nf)
            #pragma unroll
            for (int r = 0; r < 4; ++r)
                C2[(size_t)(rb + mf * 16 + r) * N + cb + nf * 16] = acc[mf][nf][r];
}

// ---------------- MFMA flash attention, K/V double-buffered, counted vmcnt ----------------
__global__ __launch_bounds__(256) void fattn_k(const u16* __restrict__ Q, const u16* __restrict__ K,
                                               const u16* __restrict__ Vt, u16* __restrict__ ctx) {
    __shared__ u16 KsA[2 * 8192];   // 2 x (64 keys x 128 k), chunk-swizzled  32KB
    __shared__ u16 VsA[2 * 8192];   // 2 x (128 d x 64 key),  chunk-swizzled  32KB
    __shared__ u16 PsA[4 * 32 * 64]; // per-wave P strip, XOR-swizzled, stride 64 = 16KB
    int t = threadIdx.x, wid = t >> 6, lane = t & 63;
    int bh = blockIdx.x;
    int yt = blockIdx.y;
    int qi = (yt < 8) ? yt : 23 - yt;
    int q0 = qi << 7;
    int wrow0 = q0 + wid * 32;
    const u16* Qb = Q + ((size_t)bh * Sc + wrow0) * HDc;
    const u16* Kb = K + (size_t)bh * Sc * HDc;
    const u16* Vb = Vt + (size_t)bh * HDc * Sc;
    int ln = lane & 15, lq = lane >> 4;
    u16* psw = PsA + wid * 2048;

    short8 aq[2][4];
    #pragma unroll
    for (int mf = 0; mf < 2; ++mf)
        #pragma unroll
        for (int ks = 0; ks < 4; ++ks)
            aq[mf][ks] = *(const short8*)(Qb + (size_t)(mf * 16 + ln) * HDc + ks * 32 + lq * 8);

    short8 onesb;
    {
        short v = (ln == 0) ? (short)0x3F80 : (short)0;
        #pragma unroll
        for (int e = 0; e < 8; ++e) onesb[e] = v;
    }

    f32x4v o[2][8] = {};
    f32x4v lacc[2] = {};

    const float sc = 0.08838834764831845f;
    const float SHIFT = 12.0f;
    int jendw = wrow0 + 31;
    int jendb = q0 + 127;
    int swz = (ln >> 1) & 3;

    // stage K(64x128) + V^T(128x64) for tile at j0s into buffer buf (8 gll16/thread)
    auto stageKV = [&](int j0s, int buf) {
        u16* Kd = KsA + buf * 8192;
        u16* Vd = VsA + buf * 8192;
        #pragma unroll
        for (int i = 0; i < 4; ++i) {
            int p = (wid * 4 + i) * 64 + lane;
            int plane = p >> 8, key = (p >> 2) & 63;
            int qc = (p & 3) ^ ((key >> 1) & 3);
            gll16(Kb + (size_t)(j0s + key) * HDc + plane * 32 + qc * 8,
                  Kd + (size_t)(wid * 4 + i) * 512);
        }
        #pragma unroll
        for (int i = 0; i < 4; ++i) {
            int p = (wid * 4 + i) * 64 + lane;
            int plane = p >> 9, d = (p >> 2) & 127;
            int qc = (p & 3) ^ ((d >> 1) & 3);
            gll16(Vb + (size_t)d * Sc + j0s + plane * 32 + qc * 8,
                  Vd + (size_t)(wid * 4 + i) * 512);
        }
    };

    stageKV(0, 0);
    for (int j0 = 0; j0 <= jendb; j0 += 64) {
        int cur = (j0 >> 6) & 1;
        if (j0 + 64 <= jendb) {
            stageKV(j0 + 64, cur ^ 1);   // prefetch next tile (other buffer; its readers
                                         // finished before the previous closing barrier)
            asm volatile("s_waitcnt vmcnt(8)" ::: "memory"); // current tile resident
        } else {
            asm volatile("s_waitcnt vmcnt(0)" ::: "memory");
        }
        BARX;

        if (j0 <= jendw) {
            const u16* Kc = KsA + cur * 8192;
            const u16* Vc = VsA + cur * 8192;
            f32x4v sf[2][4] = {};
            #pragma unroll
            for (int ks = 0; ks < 4; ++ks)
                #pragma unroll
                for (int nf = 0; nf < 4; ++nf) {
                    short8 bk = *(const short8*)(Kc + ks * 2048 + (nf * 16 + ln) * 32 + ((lq ^ swz) << 3));
                    sf[0][nf] = __builtin_amdgcn_mfma_f32_16x16x32_bf16(aq[0][ks], bk, sf[0][nf], 0, 0, 0);
                    sf[1][nf] = __builtin_amdgcn_mfma_f32_16x16x32_bf16(aq[1][ks], bk, sf[1][nf], 0, 0, 0);
                }

            bool diag = (j0 + 63 > wrow0);
            #pragma unroll
            for (int mf = 0; mf < 2; ++mf) {
                int rowb = mf * 16 + (lq << 2);
                #pragma unroll
                for (int nf = 0; nf < 4; ++nf) {
                    int col = nf * 16 + ln;
                    int ck = col >> 3, cl = col & 7;
                    #pragma unroll
                    for (int r = 0; r < 4; ++r) {
                        float p = __expf(fmaf(sf[mf][nf][r], sc, -SHIFT));
                        if (diag && (j0 + col > wrow0 + rowb + r)) p = 0.f;
                        int row = rowb + r;
                        psw[row * 64 + ((ck ^ (row & 7)) << 3) + cl] = f2bf(p);
                    }
                }
            }

            short8 ap0[2][2];
            #pragma unroll
            for (int mf = 0; mf < 2; ++mf)
                #pragma unroll
                for (int ks = 0; ks < 2; ++ks)
                    ap0[mf][ks] = *(const short8*)(psw + (mf * 16 + ln) * 64 + (((ks * 4 + lq) ^ (ln & 7)) << 3));
            #pragma unroll
            for (int ks = 0; ks < 2; ++ks) {
                lacc[0] = __builtin_amdgcn_mfma_f32_16x16x32_bf16(ap0[0][ks], onesb, lacc[0], 0, 0, 0);
                lacc[1] = __builtin_amdgcn_mfma_f32_16x16x32_bf16(ap0[1][ks], onesb, lacc[1], 0, 0, 0);
                #pragma unroll
                for (int nd = 0; nd < 8; ++nd) {
                    short8 bv = *(const short8*)(Vc + ks * 4096 + (nd * 16 + ln) * 32 + ((lq ^ swz) << 3));
                    o[0][nd] = __builtin_amdgcn_mfma_f32_16x16x32_bf16(ap0[0][ks], bv, o[0][nd], 0, 0, 0);
                    o[1][nd] = __builtin_amdgcn_mfma_f32_16x16x32_bf16(ap0[1][ks], bv, o[1][nd], 0, 0, 0);
                }
            }
        }
        BARX;
    }

    int b = bh >> 4, h = bh & 15;
    #pragma unroll
    for (int mf = 0; mf < 2; ++mf)
        #pragma unroll
        for (int r = 0; r < 4; ++r) {
            float lv = __shfl(lacc[mf][r], lane & 48, 64);
            float inv = 1.0f / lv;
            int q = wrow0 + mf * 16 + (lq << 2) + r;
            u16* cp = ctx + (((size_t)(b * Sc + q)) * Hc + h) * HDc + ln;
            #pragma unroll
            for (int nd = 0; nd < 8; ++nd)
                cp[nd * 16] = f2bf(o[mf][nd][r] * inv);
        }
}

extern "C" void kernel_launch(void* const* d_in, const int* in_sizes, int n_in,
                              void* d_out, int out_size, void* d_ws, size_t ws_size,
                              hipStream_t stream) {
    (void)in_sizes; (void)n_in; (void)out_size; (void)ws_size;
    const float* x  = (const float*)d_in[0];
    const float* Wq = (const float*)d_in[2];
    const float* Wk = (const float*)d_in[3];
    const float* Wv = (const float*)d_in[4];
    const float* Wo = (const float*)d_in[5];

    char* w = (char*)d_ws;
    u16* Wt  = (u16*)w; w += (size_t)3 * Dc * Dc * 2;
    u16* Qb  = (u16*)w; w += (size_t)Bc * Hc * Sc * HDc * 2;
    u16* Kb  = (u16*)w; w += (size_t)Bc * Hc * Sc * HDc * 2;
    u16* Vb  = (u16*)w; w += (size_t)Bc * Hc * Sc * HDc * 2;
    u16* ctx = (u16*)w; w += (size_t)Bc * Sc * Hc * HDc * 2;
    float* ctab = (float*)w; w += (size_t)Sc * 64 * 4;
    float* stab = (float*)w; w += (size_t)Sc * 64 * 4;
    u16* xb = (u16*)d_out;

    rope_tab_k<<<dim3(Sc * 64 / 256), 256, 0, stream>>>(ctab, stab);

    int nx = Bc * Sc * Dc;
    cvt_k<<<dim3(nx / 2048), 256, 0, stream>>>(x, xb, nx);

    tcvt3_k<<<dim3(Dc / 64, Dc / 64, 3), 256, 0, stream>>>(Wq, Wk, Wv, Wt, Dc, Dc);
    gemm_qkv2b<<<dim3(512), 512, 0, stream>>>(xb, Wt, Qb, Kb, Vb, ctab, stab);

    fattn_k<<<dim3(Bc * Hc, Sc / 128), 256, 0, stream>>>(Qb, Kb, Vb, ctx);

    tcvt3_k<<<dim3(Dc / 64, Dc / 64, 1), 256, 0, stream>>>(Wo, Wo, Wo, Wt, Dc, Dc);
    gemm128_op<<<dim3(Dc / 256, (Bc * Sc) / 128), 512, 0, stream>>>(
        ctx, Wt, (float*)d_out);
}

// Round 9
// 396.379 us; speedup vs baseline: 2.7341x; 2.7341x over previous
//
#include <hip/hip_runtime.h>

typedef unsigned short u16;
typedef unsigned int u32;

constexpr int Bc = 2, Sc = 2048, Dc = 2048, Hc = 16, HDc = 128;

using short8 = __attribute__((ext_vector_type(8))) short;
using f32x4v = __attribute__((ext_vector_type(4))) float;

static __device__ __forceinline__ float bf2f(u16 v) { return __uint_as_float(((u32)v) << 16); }
static __device__ __forceinline__ u16 f2bf(float f) {
    u32 u = __float_as_uint(f);
    return (u16)((u + 0x7fffu + ((u >> 16) & 1u)) >> 16);
}

// async global->LDS, 16B per lane; LDS dest = wave-uniform base + lane*16
__device__ __forceinline__ void gll16(const u16* g, u16* l) {
    __builtin_amdgcn_global_load_lds((const __attribute__((address_space(1))) void*)g,
                                     (__attribute__((address_space(3))) void*)l, 16, 0, 0);
}

#define FENCE asm volatile("" ::: "memory")
#define BARX do { FENCE; __builtin_amdgcn_s_barrier(); FENCE; } while (0)

// ---------------- RoPE cos/sin tables: [S][64] fp32 ----------------
__global__ __launch_bounds__(256) void rope_tab_k(float* __restrict__ ctab, float* __restrict__ stab) {
    int idx = blockIdx.x * 256 + threadIdx.x; // S*64 threads
    int s = idx >> 6, i = idx & 63;
    float freq = exp2f(-(float)i * 0.20762050593045952f); // 10000^(-i/64)
    float ang = (float)s * freq;
    float c, sn;
    sincosf(ang, &sn, &c);
    ctab[idx] = c;
    stab[idx] = sn;
}

// ---------------- fp32 -> bf16 bulk convert ----------------
__global__ __launch_bounds__(256) void cvt_k(const float* __restrict__ in, u16* __restrict__ out, int n) {
    int i = (blockIdx.x * 256 + threadIdx.x) * 8;
    if (i >= n) return;
    float4 a = *(const float4*)(in + i);
    float4 b = *(const float4*)(in + i + 4);
    u16 r[8] = {f2bf(a.x), f2bf(a.y), f2bf(a.z), f2bf(a.w),
                f2bf(b.x), f2bf(b.y), f2bf(b.z), f2bf(b.w)};
    *(uint4*)(out + i) = *(uint4*)r;
}

// ---------------- fp32 W (R x C) -> bf16 Wt (C x R), 64x64 tiles; z selects source ----------------
__global__ __launch_bounds__(256) void tcvt3_k(const float* __restrict__ in0, const float* __restrict__ in1,
                                               const float* __restrict__ in2, u16* __restrict__ out,
                                               int R, int C) {
    __shared__ u16 tile[64][68];
    const float* in = (blockIdx.z == 0) ? in0 : (blockIdx.z == 1) ? in1 : in2;
    u16* o = out + (size_t)blockIdx.z * R * C;
    int bx = blockIdx.x * 64, by = blockIdx.y * 64;
    int t = threadIdx.x;
    int r = t >> 4, c4 = (t & 15) * 4;
    #pragma unroll
    for (int i = 0; i < 4; ++i) {
        int row = by + r + i * 16;
        float4 v = *(const float4*)(in + (size_t)row * C + bx + c4);
        u16* d = &tile[r + i * 16][c4];
        d[0] = f2bf(v.x); d[1] = f2bf(v.y); d[2] = f2bf(v.z); d[3] = f2bf(v.w);
    }
    __syncthreads();
    int oc = t >> 4, r4 = (t & 15) * 4;
    #pragma unroll
    for (int i = 0; i < 4; ++i) {
        int orow = oc + i * 16;
        u16 v[4] = {tile[r4][orow], tile[r4 + 1][orow], tile[r4 + 2][orow], tile[r4 + 3][orow]};
        *(uint2*)&o[(size_t)(bx + orow) * R + by + r4] = *(const uint2*)v;
    }
}

// ================= QKV GEMM: 128x384, BK=32, 2-buffer, counted vmcnt ================
// A: M x K bf16 (4096 x 2048); Bt: N x K bf16 (6144 = [WqT;WkT;WvT]).
// 512 blocks; 64 KiB LDS so HW can co-schedule 2 blocks/CU (launch_bounds (512,2)
// keeps the VGPR budget >= ~110 -- (512,4) capped it at 64 and spilled acc, R8).
// Per K-tile: {stage(t+1) | vmcnt(4)=tile t resident | bar | 10 ds_read | lgk0 |
//              setprio(1) 24 MFMA setprio(0) | bar}.  vmcnt never drains mid-loop.
// Epilogue: 3 col-chunks of 128 (each = one head): Q/K +RoPE, V -> V^T (B,H,HD,S).

#define QT2(RB, KST, SB, LAST) do { \
    if (!(LAST)) { stage((KST), (SB)); \
        asm volatile("s_waitcnt vmcnt(4)" ::: "memory"); } \
    else asm volatile("s_waitcnt vmcnt(0)" ::: "memory"); \
    BARX; \
    short8 aF[4], bF[6]; \
    _Pragma("unroll") for (int m_ = 0; m_ < 4; ++m_) \
        aF[m_] = *(const short8*)((RB) + (wm * 64 + m_ * 16 + ln) * 32 + co); \
    _Pragma("unroll") for (int n_ = 0; n_ < 6; ++n_) \
        bF[n_] = *(const short8*)((RB) + 4096 + (wn * 96 + n_ * 16 + ln) * 32 + co); \
    asm volatile("s_waitcnt lgkmcnt(0)" ::: "memory"); \
    __builtin_amdgcn_s_setprio(1); \
    _Pragma("unroll") for (int m_ = 0; m_ < 4; ++m_) \
    _Pragma("unroll") for (int n_ = 0; n_ < 6; ++n_) \
        acc[m_][n_] = __builtin_amdgcn_mfma_f32_16x16x32_bf16(aF[m_], bF[n_], acc[m_][n_], 0, 0, 0); \
    __builtin_amdgcn_s_setprio(0); \
    BARX; \
} while (0)

__global__ __launch_bounds__(512, 2) void gemm_qkv2b(
        const u16* __restrict__ A, const u16* __restrict__ Bt,
        u16* __restrict__ Oq, u16* __restrict__ Ok, u16* __restrict__ Ov,
        const float* __restrict__ ctab, const float* __restrict__ stab) {
    __shared__ u16 SM[32768]; // 64 KiB: 2 buffers x {A 128x32 (8KB), B 384x32 (24KB)}
    constexpr int K = Dc;     // 2048 -> 64 K-tiles of 32
    int t = threadIdx.x, wid = t >> 6, lane = t & 63;
    int wm = wid >> 2, wn = wid & 3;          // 2 x 4 wave grid; wave tile 64 x 96
    int ln = lane & 15, lq = lane >> 4;

    // XCD-aware bijective swizzle (nwg = 512 = 8 x 64); n-major chunks per XCD
    int lin = blockIdx.x;
    int swzb = (lin & 7) * 64 + (lin >> 3);
    int n0 = (swzb >> 5) * 384;      // 16 n-cols
    int m0 = (swzb & 31) * 128;      // 32 m-rows

    // stage K-tile kt into buffer b. LDS written LINEARLY by global_load_lds;
    // read-side chunk swizzle (cs ^= (row>>1)&3) realized on the GLOBAL source.
    auto stage = [&](int kt, int b) {
        u16* Ad = SM + b * 16384;
        u16* Bd = SM + b * 16384 + 4096;
        {
            int row = t >> 2, cs = t & 3; // A: 128x32, 512 chunks of 16B
            gll16(A + (size_t)(m0 + row) * K + kt * 32 + ((cs ^ ((row >> 1) & 3)) << 3),
                  Ad + (wid * 64) * 8);
        }
        #pragma unroll
        for (int L = 0; L < 3; ++L) {
            int ci = L * 512 + t;         // B: 384x32, 1536 chunks
            int row = ci >> 2, cs = ci & 3;
            gll16(Bt + (size_t)(n0 + row) * K + kt * 32 + ((cs ^ ((row >> 1) & 3)) << 3),
                  Bd + (L * 512 + wid * 64) * 8);
        }
    };

    int co = ((lq ^ ((ln >> 1) & 3)) << 3); // swizzled read chunk (row bases are 0 mod 8)
    f32x4v acc[4][6] = {};

    // prologue: tile 0 staged; residency enforced by first QT2's vmcnt(4)
    stage(0, 0);

    // main: alternate buffers; stage(t+1) at tile t; last tile drains
    #pragma unroll 1
    for (int kt = 0; kt < 62; kt += 2) {
        QT2(SM,         kt + 1, 1, 0);
        QT2(SM + 16384, kt + 2, 0, 0);
    }
    QT2(SM,         63, 1, 0);  // tile 62, stage 63
    QT2(SM + 16384,  0, 0, 1);  // tile 63 (tail: vmcnt(0))

    // ---- epilogue: 3 col-chunks of 128 through a 128 x 130 bf16 strip ----
    int b_ = m0 >> 11;
    int s0 = m0 & (Sc - 1);
    u16* Es = SM;
    const int ESTR = 130;

    for (int c = 0; c < 3; ++c) {
        #pragma unroll
        for (int nf = 0; nf < 6; ++nf) {
            int cg = wn * 96 + nf * 16;
            if ((cg >> 7) == c) {
                int col = cg & 127;
                #pragma unroll
                for (int mf = 0; mf < 4; ++mf)
                    #pragma unroll
                    for (int r = 0; r < 4; ++r)
                        Es[(wm * 64 + mf * 16 + (lq << 2) + r) * ESTR + col + ln] =
                            f2bf(acc[mf][nf][r]);
            }
        }
        __syncthreads();

        int gcol = n0 + c * 128;
        int which = gcol >> 11;          // 0=Q,1=K,2=V
        int h = (gcol & 2047) >> 7;
        if (which < 2) {
            // Q or K +RoPE: thread t -> row rh=t>>2, half h2=t&1, j-half jh=(t>>1)&1
            u16* dst0 = which ? Ok : Oq;
            int rh = t >> 2, h2 = t & 1, jh = (t >> 1) & 1;
            int s = s0 + rh;
            const u16* rowp = Es + rh * ESTR;
            const float* ct = ctab + (size_t)s * 64;
            const float* st = stab + (size_t)s * 64;
            u16* dp = dst0 + (((size_t)(b_ * Hc + h)) * Sc + s) * HDc + h2 * 64;
            #pragma unroll
            for (int j8 = jh * 32; j8 < jh * 32 + 32; j8 += 8) {
                uint4 aa = *(const uint4*)(rowp + j8);
                uint4 bb = *(const uint4*)(rowp + 64 + j8);
                const u16* ap8 = (const u16*)&aa;
                const u16* bp8 = (const u16*)&bb;
                float4 c0f = *(const float4*)(ct + j8);
                float4 c1f = *(const float4*)(ct + j8 + 4);
                float4 sn0 = *(const float4*)(st + j8);
                float4 sn1 = *(const float4*)(st + j8 + 4);
                float cc[8] = {c0f.x, c0f.y, c0f.z, c0f.w, c1f.x, c1f.y, c1f.z, c1f.w};
                float ss[8] = {sn0.x, sn0.y, sn0.z, sn0.w, sn1.x, sn1.y, sn1.z, sn1.w};
                u16 ov[8];
                #pragma unroll
                for (int e = 0; e < 8; ++e) {
                    float x1 = bf2f(ap8[e]), x2 = bf2f(bp8[e]);
                    ov[e] = h2 ? f2bf(x2 * cc[e] + x1 * ss[e]) : f2bf(x1 * cc[e] - x2 * ss[e]);
                }
                *(uint4*)(dp + j8) = *(const uint4*)ov;
            }
        } else {
            // V^T: thread t -> col d=t>>2, s-quarter sh=t&3 (32 rows each)
            int d = t >> 2, sh = t & 3;
            u16* dp = Ov + (((size_t)(b_ * Hc + h)) * HDc + d) * Sc + s0 + sh * 32;
            #pragma unroll
            for (int r8 = 0; r8 < 32; r8 += 8) {
                u16 ov[8];
                #pragma unroll
                for (int e = 0; e < 8; ++e)
                    ov[e] = Es[(sh * 32 + r8 + e) * ESTR + d];
                *(uint4*)(dp + r8) = *(const uint4*)ov;
            }
        }
        __syncthreads();
    }
}

// ================= out-proj GEMM: 128x256 BK=64 8-wave triple-buffer ================
// A = ctx bf16 (4096 x 2048), Bt = Wo^T bf16 (2048 x 2048), C2 fp32 (4096 x 2048).
// grid 8 x 32 = 256 blocks = exactly 1 round of 256 CUs.

#define RDA8(P) do { _Pragma("unroll") for (int m_ = 0; m_ < 4; ++m_) { \
    aG[m_][0] = *(const short8*)((P) + m_ * 1024 + co0); \
    aG[m_][1] = *(const short8*)((P) + m_ * 1024 + co1); } } while (0)

#define RDB2(P, nh) do { _Pragma("unroll") for (int j_ = 0; j_ < 2; ++j_) { \
    bG[j_][0] = *(const short8*)((P) + ((nh) * 2 + j_) * 1024 + co0); \
    bG[j_][1] = *(const short8*)((P) + ((nh) * 2 + j_) * 1024 + co1); } } while (0)

#define MFQ8(nh) do { _Pragma("unroll") for (int m_ = 0; m_ < 4; ++m_) \
    _Pragma("unroll") for (int j_ = 0; j_ < 2; ++j_) { \
    f32x4v& c_ = acc[m_][(nh) * 2 + j_]; \
    c_ = __builtin_amdgcn_mfma_f32_16x16x32_bf16(aG[m_][0], bG[j_][0], c_, 0, 0, 0); \
    c_ = __builtin_amdgcn_mfma_f32_16x16x32_bf16(aG[m_][1], bG[j_][1], c_, 0, 0, 0); } } while (0)

#define PT(nh) do { BARX; \
    asm volatile("s_waitcnt lgkmcnt(0)" ::: "memory"); \
    __builtin_amdgcn_s_setprio(1); MFQ8(nh); __builtin_amdgcn_s_setprio(0); \
    BARX; } while (0)

#define KTILE(aRb, bRb, KST, ADST, BDST, VW) do { \
    RDA8(aRb); RDB2(bRb, 0); \
    if ((KST) >= 0) stageA(KST, ADST); \
    PT(0); \
    RDB2(bRb, 1); \
    if ((KST) >= 0) stageB(KST, BDST); \
    if ((VW) == 6) asm volatile("s_waitcnt vmcnt(6)" ::: "memory"); \
    else if ((VW) == 0) asm volatile("s_waitcnt vmcnt(0)" ::: "memory"); \
    PT(1); } while (0)

__global__ __launch_bounds__(512, 2) void gemm128_op(
        const u16* __restrict__ A, const u16* __restrict__ Bt, float* __restrict__ C2) {
    __shared__ u16 SM[73728]; // 144 KiB: A x3 (16KB each) + B x3 (32KB each)
    constexpr int K = Dc;     // 2048 -> 32 K-tiles of 64
    constexpr int NT = 32;
    constexpr int N = Dc;
    int t = threadIdx.x, wid = t >> 6, lane = t & 63;
    int wm = wid >> 2, wn = wid & 3;          // 2 x 4 wave grid; wave tile 64 x 64
    int ln = lane & 15, lq = lane >> 4;

    // XCD-aware bijective swizzle (nwg = 256)
    int nx = gridDim.x; // 8
    int lin = blockIdx.y * nx + blockIdx.x;
    int cpx = (nx * gridDim.y) >> 3; // 32
    int swzb = (lin & 7) * cpx + (lin >> 3);
    int n0 = (swzb % nx) << 8;
    int m0 = (swzb / nx) << 7;

    u16* As0 = SM;
    u16* As1 = SM + 8192;
    u16* As2 = SM + 16384;
    u16* Bs0 = SM + 24576;
    u16* Bs1 = SM + 40960;
    u16* Bs2 = SM + 57344;

    auto stageA = [&](int kt, u16* dst) {
        #pragma unroll
        for (int L = 0; L < 2; ++L) {
            int ch16 = L * 512 + wid * 64 + lane; // 16B-chunk index, 128x64 tile
            int row = ch16 >> 3, ch = ch16 & 7;
            gll16(A + (size_t)(m0 + row) * K + kt * 64 + ((ch ^ (row & 7)) << 3),
                  dst + (L * 512 + wid * 64) * 8);
        }
    };
    auto stageB = [&](int kt, u16* dst) {
        #pragma unroll
        for (int L = 0; L < 4; ++L) {
            int ch16 = L * 512 + wid * 64 + lane; // 16B-chunk index, 256x64 tile
            int row = ch16 >> 3, ch = ch16 & 7;
            gll16(Bt + (size_t)(n0 + row) * K + kt * 64 + ((ch ^ (row & 7)) << 3),
                  dst + (L * 512 + wid * 64) * 8);
        }
    };

    const u16* aR0 = As0 + (wm * 64 + ln) * 64;
    const u16* aR1 = As1 + (wm * 64 + ln) * 64;
    const u16* aR2 = As2 + (wm * 64 + ln) * 64;
    const u16* bR0 = Bs0 + (wn * 64 + ln) * 64;
    const u16* bR1 = Bs1 + (wn * 64 + ln) * 64;
    const u16* bR2 = Bs2 + (wn * 64 + ln) * 64;
    int sw = ln & 7;
    int co0 = (lq ^ sw) << 3;        // k-slice 0 chunk (swizzled), u16 units
    int co1 = ((4 | lq) ^ sw) << 3;  // k-slice 1 chunk

    short8 aG[4][2], bG[2][2];
    f32x4v acc[4][4] = {};

    stageA(0, As0); stageB(0, Bs0);
    stageA(1, As1); stageB(1, Bs1);
    asm volatile("s_waitcnt vmcnt(6)" ::: "memory"); // kt0 resident, kt1 in flight
    BARX;

    for (int k3 = 0; k3 < NT - 2; k3 += 3) {
        KTILE(aR0, bR0, k3 + 2, As2, Bs2, 6);
        KTILE(aR1, bR1, k3 + 3, As0, Bs0, 6);
        KTILE(aR2, bR2, k3 + 4, As1, Bs1, 6);
    }
    KTILE(aR0, bR0, -1, As0, Bs0, 0);  // kt=30; drain so kt31 resident
    KTILE(aR1, bR1, -1, As0, Bs0, -1); // kt=31

    int rb = m0 + wm * 64 + (lq << 2);
    int cb = n0 + wn * 64 + ln;
    #pragma unroll
    for (int mf = 0; mf < 4; ++mf)
        #pragma unroll
        for (int nf = 0; nf < 4; ++nf)
            #pragma unroll
            for (int r = 0; r < 4; ++r)
                C2[(size_t)(rb + mf * 16 + r) * N + cb + nf * 16] = acc[mf][nf][r];
}

// ---------------- MFMA flash attention, K/V double-buffered, counted vmcnt ----------------
__global__ __launch_bounds__(256) void fattn_k(const u16* __restrict__ Q, const u16* __restrict__ K,
                                               const u16* __restrict__ Vt, u16* __restrict__ ctx) {
    __shared__ u16 KsA[2 * 8192];   // 2 x (64 keys x 128 k), chunk-swizzled  32KB
    __shared__ u16 VsA[2 * 8192];   // 2 x (128 d x 64 key),  chunk-swizzled  32KB
    __shared__ u16 PsA[4 * 32 * 64]; // per-wave P strip, XOR-swizzled, stride 64 = 16KB
    int t = threadIdx.x, wid = t >> 6, lane = t & 63;
    int bh = blockIdx.x;
    int yt = blockIdx.y;
    int qi = (yt < 8) ? yt : 23 - yt;
    int q0 = qi << 7;
    int wrow0 = q0 + wid * 32;
    const u16* Qb = Q + ((size_t)bh * Sc + wrow0) * HDc;
    const u16* Kb = K + (size_t)bh * Sc * HDc;
    const u16* Vb = Vt + (size_t)bh * HDc * Sc;
    int ln = lane & 15, lq = lane >> 4;
    u16* psw = PsA + wid * 2048;

    short8 aq[2][4];
    #pragma unroll
    for (int mf = 0; mf < 2; ++mf)
        #pragma unroll
        for (int ks = 0; ks < 4; ++ks)
            aq[mf][ks] = *(const short8*)(Qb + (size_t)(mf * 16 + ln) * HDc + ks * 32 + lq * 8);

    short8 onesb;
    {
        short v = (ln == 0) ? (short)0x3F80 : (short)0;
        #pragma unroll
        for (int e = 0; e < 8; ++e) onesb[e] = v;
    }

    f32x4v o[2][8] = {};
    f32x4v lacc[2] = {};

    const float sc = 0.08838834764831845f;
    const float SHIFT = 12.0f;
    int jendw = wrow0 + 31;
    int jendb = q0 + 127;
    int swz = (ln >> 1) & 3;

    // stage K(64x128) + V^T(128x64) for tile at j0s into buffer buf (8 gll16/thread)
    auto stageKV = [&](int j0s, int buf) {
        u16* Kd = KsA + buf * 8192;
        u16* Vd = VsA + buf * 8192;
        #pragma unroll
        for (int i = 0; i < 4; ++i) {
            int p = (wid * 4 + i) * 64 + lane;
            int plane = p >> 8, key = (p >> 2) & 63;
            int qc = (p & 3) ^ ((key >> 1) & 3);
            gll16(Kb + (size_t)(j0s + key) * HDc + plane * 32 + qc * 8,
                  Kd + (size_t)(wid * 4 + i) * 512);
        }
        #pragma unroll
        for (int i = 0; i < 4; ++i) {
            int p = (wid * 4 + i) * 64 + lane;
            int plane = p >> 9, d = (p >> 2) & 127;
            int qc = (p & 3) ^ ((d >> 1) & 3);
            gll16(Vb + (size_t)d * Sc + j0s + plane * 32 + qc * 8,
                  Vd + (size_t)(wid * 4 + i) * 512);
        }
    };

    stageKV(0, 0);
    for (int j0 = 0; j0 <= jendb; j0 += 64) {
        int cur = (j0 >> 6) & 1;
        if (j0 + 64 <= jendb) {
            stageKV(j0 + 64, cur ^ 1);   // prefetch next tile (other buffer; its readers
                                         // finished before the previous closing barrier)
            asm volatile("s_waitcnt vmcnt(8)" ::: "memory"); // current tile resident
        } else {
            asm volatile("s_waitcnt vmcnt(0)" ::: "memory");
        }
        BARX;

        if (j0 <= jendw) {
            const u16* Kc = KsA + cur * 8192;
            const u16* Vc = VsA + cur * 8192;
            f32x4v sf[2][4] = {};
            #pragma unroll
            for (int ks = 0; ks < 4; ++ks)
                #pragma unroll
                for (int nf = 0; nf < 4; ++nf) {
                    short8 bk = *(const short8*)(Kc + ks * 2048 + (nf * 16 + ln) * 32 + ((lq ^ swz) << 3));
                    sf[0][nf] = __builtin_amdgcn_mfma_f32_16x16x32_bf16(aq[0][ks], bk, sf[0][nf], 0, 0, 0);
                    sf[1][nf] = __builtin_amdgcn_mfma_f32_16x16x32_bf16(aq[1][ks], bk, sf[1][nf], 0, 0, 0);
                }

            bool diag = (j0 + 63 > wrow0);
            #pragma unroll
            for (int mf = 0; mf < 2; ++mf) {
                int rowb = mf * 16 + (lq << 2);
                #pragma unroll
                for (int nf = 0; nf < 4; ++nf) {
                    int col = nf * 16 + ln;
                    int ck = col >> 3, cl = col & 7;
                    #pragma unroll
                    for (int r = 0; r < 4; ++r) {
                        float p = __expf(fmaf(sf[mf][nf][r], sc, -SHIFT));
                        if (diag && (j0 + col > wrow0 + rowb + r)) p = 0.f;
                        int row = rowb + r;
                        psw[row * 64 + ((ck ^ (row & 7)) << 3) + cl] = f2bf(p);
                    }
                }
            }

            short8 ap0[2][2];
            #pragma unroll
            for (int mf = 0; mf < 2; ++mf)
                #pragma unroll
                for (int ks = 0; ks < 2; ++ks)
                    ap0[mf][ks] = *(const short8*)(psw + (mf * 16 + ln) * 64 + (((ks * 4 + lq) ^ (ln & 7)) << 3));
            #pragma unroll
            for (int ks = 0; ks < 2; ++ks) {
                lacc[0] = __builtin_amdgcn_mfma_f32_16x16x32_bf16(ap0[0][ks], onesb, lacc[0], 0, 0, 0);
                lacc[1] = __builtin_amdgcn_mfma_f32_16x16x32_bf16(ap0[1][ks], onesb, lacc[1], 0, 0, 0);
                #pragma unroll
                for (int nd = 0; nd < 8; ++nd) {
                    short8 bv = *(const short8*)(Vc + ks * 4096 + (nd * 16 + ln) * 32 + ((lq ^ swz) << 3));
                    o[0][nd] = __builtin_amdgcn_mfma_f32_16x16x32_bf16(ap0[0][ks], bv, o[0][nd], 0, 0, 0);
                    o[1][nd] = __builtin_amdgcn_mfma_f32_16x16x32_bf16(ap0[1][ks], bv, o[1][nd], 0, 0, 0);
                }
            }
        }
        BARX;
    }

    int b = bh >> 4, h = bh & 15;
    #pragma unroll
    for (int mf = 0; mf < 2; ++mf)
        #pragma unroll
        for (int r = 0; r < 4; ++r) {
            float lv = __shfl(lacc[mf][r], lane & 48, 64);
            float inv = 1.0f / lv;
            int q = wrow0 + mf * 16 + (lq << 2) + r;
            u16* cp = ctx + (((size_t)(b * Sc + q)) * Hc + h) * HDc + ln;
            #pragma unroll
            for (int nd = 0; nd < 8; ++nd)
                cp[nd * 16] = f2bf(o[mf][nd][r] * inv);
        }
}

extern "C" void kernel_launch(void* const* d_in, const int* in_sizes, int n_in,
                              void* d_out, int out_size, void* d_ws, size_t ws_size,
                              hipStream_t stream) {
    (void)in_sizes; (void)n_in; (void)out_size; (void)ws_size;
    const float* x  = (const float*)d_in[0];
    const float* Wq = (const float*)d_in[2];
    const float* Wk = (const float*)d_in[3];
    const float* Wv = (const float*)d_in[4];
    const float* Wo = (const float*)d_in[5];

    char* w = (char*)d_ws;
    u16* Wt  = (u16*)w; w += (size_t)3 * Dc * Dc * 2;
    u16* Qb  = (u16*)w; w += (size_t)Bc * Hc * Sc * HDc * 2;
    u16* Kb  = (u16*)w; w += (size_t)Bc * Hc * Sc * HDc * 2;
    u16* Vb  = (u16*)w; w += (size_t)Bc * Hc * Sc * HDc * 2;
    u16* ctx = (u16*)w; w += (size_t)Bc * Sc * Hc * HDc * 2;
    float* ctab = (float*)w; w += (size_t)Sc * 64 * 4;
    float* stab = (float*)w; w += (size_t)Sc * 64 * 4;
    u16* xb = (u16*)d_out;

    rope_tab_k<<<dim3(Sc * 64 / 256), 256, 0, stream>>>(ctab, stab);

    int nx = Bc * Sc * Dc;
    cvt_k<<<dim3(nx / 2048), 256, 0, stream>>>(x, xb, nx);

    tcvt3_k<<<dim3(Dc / 64, Dc / 64, 3), 256, 0, stream>>>(Wq, Wk, Wv, Wt, Dc, Dc);
    gemm_qkv2b<<<dim3(512), 512, 0, stream>>>(xb, Wt, Qb, Kb, Vb, ctab, stab);

    fattn_k<<<dim3(Bc * Hc, Sc / 128), 256, 0, stream>>>(Qb, Kb, Vb, ctx);

    tcvt3_k<<<dim3(Dc / 64, Dc / 64, 1), 256, 0, stream>>>(Wo, Wo, Wo, Wt, Dc, Dc);
    gemm128_op<<<dim3(Dc / 256, (Bc * Sc) / 128), 512, 0, stream>>>(
        ctx, Wt, (float*)d_out);
}